// Round 1
// baseline (36.122 us; speedup 1.0000x reference)
//
#include <hip/hip_runtime.h>

// MeanPoolingWithoutPadding: features [B,S,D] f32, lengths [B] i32 (harness
// converts integers to int32). out [B,D] f32 = sum_{s<len[b]} f[b,s,:] / len[b].
// B=64, S=2048, D=512 (D compile-time for float4 addressing).

#define DDIM 512
#define TPB  128          // DDIM/4 threads, one float4 per thread
#define NSPLIT_MAX 32

__device__ __forceinline__ void acc4(float4& a, const float4& v) {
    a.x += v.x; a.y += v.y; a.z += v.z; a.w += v.w;
}

// Partial sums: grid (B, nsplit), block TPB. ws[(b*nsplit+split)*DDIM + d]
__global__ void __launch_bounds__(TPB)
pool_partial(const float* __restrict__ feat, const int* __restrict__ lengths,
             float* __restrict__ ws, int S, int nsplit, int chunk) {
    const int b     = blockIdx.x;
    const int split = blockIdx.y;
    const int tid   = threadIdx.x;
    const int len   = lengths[b];

    const int s0 = split * chunk;
    const int s1 = min(s0 + chunk, len);

    float4 a0 = {0.f, 0.f, 0.f, 0.f};
    float4 a1 = {0.f, 0.f, 0.f, 0.f};
    float4 a2 = {0.f, 0.f, 0.f, 0.f};
    float4 a3 = {0.f, 0.f, 0.f, 0.f};

    const float4* __restrict__ base =
        reinterpret_cast<const float4*>(feat + (size_t)b * S * DDIM) + tid;
    const int ld4 = DDIM / 4;  // float4 stride per s row

    int s = s0;
    for (; s + 3 < s1; s += 4) {
        float4 v0 = base[(size_t)(s + 0) * ld4];
        float4 v1 = base[(size_t)(s + 1) * ld4];
        float4 v2 = base[(size_t)(s + 2) * ld4];
        float4 v3 = base[(size_t)(s + 3) * ld4];
        acc4(a0, v0); acc4(a1, v1); acc4(a2, v2); acc4(a3, v3);
    }
    for (; s < s1; ++s) {
        float4 v = base[(size_t)s * ld4];
        acc4(a0, v);
    }
    acc4(a0, a1); acc4(a2, a3); acc4(a0, a2);

    // Always write (ws is poisoned 0xAA; blocks past len must contribute 0).
    float4* wsp = reinterpret_cast<float4*>(ws + ((size_t)b * nsplit + split) * DDIM) + tid;
    *wsp = a0;
}

// Final reduce: grid B, block TPB.
__global__ void __launch_bounds__(TPB)
pool_final(const float* __restrict__ ws, const int* __restrict__ lengths,
           float* __restrict__ out, int nsplit) {
    const int b   = blockIdx.x;
    const int tid = threadIdx.x;
    float4 acc = {0.f, 0.f, 0.f, 0.f};
    const float4* wsp = reinterpret_cast<const float4*>(ws + (size_t)b * nsplit * DDIM) + tid;
    for (int p = 0; p < nsplit; ++p) {
        acc4(acc, wsp[(size_t)p * (DDIM / 4)]);
    }
    const float inv = 1.0f / (float)lengths[b];
    float4 r = {acc.x * inv, acc.y * inv, acc.z * inv, acc.w * inv};
    reinterpret_cast<float4*>(out + (size_t)b * DDIM)[tid] = r;
}

// Fallback (no/too-small workspace): one block per b, full S loop.
__global__ void __launch_bounds__(TPB)
pool_direct(const float* __restrict__ feat, const int* __restrict__ lengths,
            float* __restrict__ out, int S) {
    const int b   = blockIdx.x;
    const int tid = threadIdx.x;
    const int len = lengths[b];
    float4 a0 = {0.f, 0.f, 0.f, 0.f};
    float4 a1 = {0.f, 0.f, 0.f, 0.f};
    float4 a2 = {0.f, 0.f, 0.f, 0.f};
    float4 a3 = {0.f, 0.f, 0.f, 0.f};
    const float4* __restrict__ base =
        reinterpret_cast<const float4*>(feat + (size_t)b * S * DDIM) + tid;
    const int ld4 = DDIM / 4;
    int s = 0;
    for (; s + 3 < len; s += 4) {
        float4 v0 = base[(size_t)(s + 0) * ld4];
        float4 v1 = base[(size_t)(s + 1) * ld4];
        float4 v2 = base[(size_t)(s + 2) * ld4];
        float4 v3 = base[(size_t)(s + 3) * ld4];
        acc4(a0, v0); acc4(a1, v1); acc4(a2, v2); acc4(a3, v3);
    }
    for (; s < len; ++s) { float4 v = base[(size_t)s * ld4]; acc4(a0, v); }
    acc4(a0, a1); acc4(a2, a3); acc4(a0, a2);
    const float inv = 1.0f / (float)len;
    float4 r = {a0.x * inv, a0.y * inv, a0.z * inv, a0.w * inv};
    reinterpret_cast<float4*>(out + (size_t)b * DDIM)[tid] = r;
}

extern "C" void kernel_launch(void* const* d_in, const int* in_sizes, int n_in,
                              void* d_out, int out_size, void* d_ws, size_t ws_size,
                              hipStream_t stream) {
    const float* feat    = (const float*)d_in[0];
    const int*   lengths = (const int*)d_in[1];
    float*       out     = (float*)d_out;

    const int B = in_sizes[1];                       // 64
    const int S = in_sizes[0] / (B * DDIM);          // 2048

    // Workspace needed per split-slice: B * DDIM * 4 bytes.
    const size_t per_split = (size_t)B * DDIM * sizeof(float);
    int nsplit = (int)(ws_size / per_split);
    if (nsplit > NSPLIT_MAX) nsplit = NSPLIT_MAX;

    if (nsplit >= 2) {
        const int chunk = (S + nsplit - 1) / nsplit;
        float* ws = (float*)d_ws;
        dim3 grid1(B, nsplit);
        pool_partial<<<grid1, TPB, 0, stream>>>(feat, lengths, ws, S, nsplit, chunk);
        pool_final<<<B, TPB, 0, stream>>>(ws, lengths, out, nsplit);
    } else {
        pool_direct<<<B, TPB, 0, stream>>>(feat, lengths, out, S);
    }
}

// Round 2
// 29.620 us; speedup vs baseline: 1.2195x; 1.2195x over previous
//
#include <hip/hip_runtime.h>

// MeanPoolingWithoutPadding: features [B,S,D] f32, lengths [B] i32,
// out [B,D] f32 = sum_{s<len[b]} f[b,s,:] / len[b].  B=64, S=2048, D=512.
//
// Two-phase split-S reduction (deterministic, no float atomics):
//   pool_partial: grid (B, nsplit=64), 128 thr; each block sums a 32-row
//     chunk (clamped to len) into ws[(b*nsplit+split)*D + d]. Unroll 8 ->
//     16 KB of loads in flight per block for straggler-tail BW.
//   pool_final:   grid B, 512 thr; 4 p-groups of 128 lanes reduce ws with
//     an LDS combine, divide by len, store.

#define DDIM 512
#define TPB  128
#define NSPLIT_MAX 64

__device__ __forceinline__ void acc4(float4& a, const float4& v) {
    a.x += v.x; a.y += v.y; a.z += v.z; a.w += v.w;
}

__global__ void __launch_bounds__(TPB)
pool_partial(const float* __restrict__ feat, const int* __restrict__ lengths,
             float* __restrict__ ws, int S, int nsplit, int chunk) {
    const int b     = blockIdx.x;
    const int split = blockIdx.y;
    const int tid   = threadIdx.x;
    const int len   = lengths[b];

    const int s0 = split * chunk;
    const int s1 = min(s0 + chunk, len);

    float4 a0 = {0.f, 0.f, 0.f, 0.f};
    float4 a1 = {0.f, 0.f, 0.f, 0.f};
    float4 a2 = {0.f, 0.f, 0.f, 0.f};
    float4 a3 = {0.f, 0.f, 0.f, 0.f};

    const float4* __restrict__ base =
        reinterpret_cast<const float4*>(feat + (size_t)b * S * DDIM) + tid;
    const int ld4 = DDIM / 4;  // float4 stride per s row

    int s = s0;
    for (; s + 7 < s1; s += 8) {
        float4 v0 = base[(size_t)(s + 0) * ld4];
        float4 v1 = base[(size_t)(s + 1) * ld4];
        float4 v2 = base[(size_t)(s + 2) * ld4];
        float4 v3 = base[(size_t)(s + 3) * ld4];
        float4 v4 = base[(size_t)(s + 4) * ld4];
        float4 v5 = base[(size_t)(s + 5) * ld4];
        float4 v6 = base[(size_t)(s + 6) * ld4];
        float4 v7 = base[(size_t)(s + 7) * ld4];
        acc4(a0, v0); acc4(a1, v1); acc4(a2, v2); acc4(a3, v3);
        acc4(a0, v4); acc4(a1, v5); acc4(a2, v6); acc4(a3, v7);
    }
    for (; s < s1; ++s) {
        float4 v = base[(size_t)s * ld4];
        acc4(a0, v);
    }
    acc4(a0, a1); acc4(a2, a3); acc4(a0, a2);

    // Always write (ws is poisoned 0xAA; inactive blocks must contribute 0).
    float4* wsp = reinterpret_cast<float4*>(ws + ((size_t)b * nsplit + split) * DDIM) + tid;
    *wsp = a0;
}

#define TPB2 512
__global__ void __launch_bounds__(TPB2)
pool_final(const float* __restrict__ ws, const int* __restrict__ lengths,
           float* __restrict__ out, int nsplit) {
    const int b    = blockIdx.x;
    const int tid  = threadIdx.x;
    const int grp  = tid >> 7;     // 0..3
    const int lane = tid & 127;

    float4 acc = {0.f, 0.f, 0.f, 0.f};
    const float4* wsp = reinterpret_cast<const float4*>(ws + (size_t)b * nsplit * DDIM) + lane;
    #pragma unroll 4
    for (int p = grp; p < nsplit; p += 4) {
        acc4(acc, wsp[(size_t)p * (DDIM / 4)]);
    }

    __shared__ float4 red[4][TPB];
    red[grp][lane] = acc;
    __syncthreads();
    if (grp == 0) {
        acc4(acc, red[1][lane]);
        acc4(acc, red[2][lane]);
        acc4(acc, red[3][lane]);
        const float inv = 1.0f / (float)lengths[b];
        float4 r = {acc.x * inv, acc.y * inv, acc.z * inv, acc.w * inv};
        reinterpret_cast<float4*>(out + (size_t)b * DDIM)[lane] = r;
    }
}

// Fallback (too-small workspace): one block per b, full S loop.
__global__ void __launch_bounds__(TPB)
pool_direct(const float* __restrict__ feat, const int* __restrict__ lengths,
            float* __restrict__ out, int S) {
    const int b   = blockIdx.x;
    const int tid = threadIdx.x;
    const int len = lengths[b];
    float4 a0 = {0.f, 0.f, 0.f, 0.f};
    float4 a1 = {0.f, 0.f, 0.f, 0.f};
    float4 a2 = {0.f, 0.f, 0.f, 0.f};
    float4 a3 = {0.f, 0.f, 0.f, 0.f};
    const float4* __restrict__ base =
        reinterpret_cast<const float4*>(feat + (size_t)b * S * DDIM) + tid;
    const int ld4 = DDIM / 4;
    int s = 0;
    for (; s + 3 < len; s += 4) {
        float4 v0 = base[(size_t)(s + 0) * ld4];
        float4 v1 = base[(size_t)(s + 1) * ld4];
        float4 v2 = base[(size_t)(s + 2) * ld4];
        float4 v3 = base[(size_t)(s + 3) * ld4];
        acc4(a0, v0); acc4(a1, v1); acc4(a2, v2); acc4(a3, v3);
    }
    for (; s < len; ++s) { float4 v = base[(size_t)s * ld4]; acc4(a0, v); }
    acc4(a0, a1); acc4(a2, a3); acc4(a0, a2);
    const float inv = 1.0f / (float)len;
    float4 r = {a0.x * inv, a0.y * inv, a0.z * inv, a0.w * inv};
    reinterpret_cast<float4*>(out + (size_t)b * DDIM)[tid] = r;
}

extern "C" void kernel_launch(void* const* d_in, const int* in_sizes, int n_in,
                              void* d_out, int out_size, void* d_ws, size_t ws_size,
                              hipStream_t stream) {
    const float* feat    = (const float*)d_in[0];
    const int*   lengths = (const int*)d_in[1];
    float*       out     = (float*)d_out;

    const int B = in_sizes[1];                       // 64
    const int S = in_sizes[0] / (B * DDIM);          // 2048

    const size_t per_split = (size_t)B * DDIM * sizeof(float);
    int nsplit = (int)(ws_size / per_split);
    if (nsplit > NSPLIT_MAX) nsplit = NSPLIT_MAX;

    if (nsplit >= 2) {
        const int chunk = (S + nsplit - 1) / nsplit;
        float* ws = (float*)d_ws;
        dim3 grid1(B, nsplit);
        pool_partial<<<grid1, TPB, 0, stream>>>(feat, lengths, ws, S, nsplit, chunk);
        pool_final<<<B, TPB2, 0, stream>>>(ws, lengths, out, nsplit);
    } else {
        pool_direct<<<B, TPB, 0, stream>>>(feat, lengths, out, S);
    }
}